// Round 6
// baseline (239.659 us; speedup 1.0000x reference)
//
#include <hip/hip_runtime.h>

#define B_ 4
#define D_ 128
#define H_ 128
#define W_ 32
#define CI 32
#define CO 64
#define OD 64
#define OH 64
#define OW 32
#define S_SPATIAL (OD*OH*OW)   // 131072
#define EPS 1e-5f
#define ALPHA 0.2f

#define XR 9                    // x-tile rows per kd slice (ih span of an oh-quad)
#define XC 34                   // x-tile cols incl. W halo (iw=-1..32 zero-padded)
#define XUNITS (4*XR*XC)        // 1224 8-ci units of 16B

typedef __attribute__((ext_vector_type(8))) short short8;
typedef __attribute__((ext_vector_type(4))) float f32x4;

__device__ inline short f2bf(float f) {
    // RNE float->bf16
    union { float f; unsigned u; } v; v.f = f;
    unsigned r = v.u + 0x7FFFu + ((v.u >> 16) & 1u);
    return (short)(r >> 16);
}

__device__ inline short8 pack8(float4 a, float4 b) {
    short8 r;
    r[0]=f2bf(a.x); r[1]=f2bf(a.y); r[2]=f2bf(a.z); r[3]=f2bf(a.w);
    r[4]=f2bf(b.x); r[5]=f2bf(b.y); r[6]=f2bf(b.z); r[7]=f2bf(b.w);
    return r;
}

__global__ __launch_bounds__(512) void zero_ws_kernel(float* ws) {
    ws[threadIdx.x] = 0.f;   // 512 floats: sums + sumsqs
}

// Repack w[b,kd,kh,kw,ci,co] f32 -> bf16 lane-ordered B-fragments.
__global__ __launch_bounds__(64) void wprep_kernel(const float* __restrict__ w,
                                                   short* __restrict__ wp) {
    int blk = blockIdx.x;          // ((b*27+tap)*4+nf)
    int nf  = blk & 3;
    int tb  = blk >> 2;            // b*27+tap
    int l   = threadIdx.x;
    int l15 = l & 15, lhi = l >> 4;
    const float* wsrc = w + (size_t)tb * (CI*CO);   // [ci][co]
    short8 v;
#pragma unroll
    for (int j = 0; j < 8; ++j)
        v[j] = f2bf(wsrc[(lhi*8 + j)*CO + nf*16 + l15]);
    *(short8*)(wp + (size_t)blk*512 + l*8) = v;
}

// Implicit-GEMM conv with LDS-staged bf16 x tile, kd-streamed.
// Block = (b, od, oh-quad); wave wv owns oh row oh0+wv (M=32: ow 0-15, 16-31).
// Small tile -> high block residency; cross-block TLP hides staging latency (m114).
// Fused InstanceNorm stats via shfl + LDS + one atomic pair per block.
__global__ __launch_bounds__(256) void conv_mfma_kernel(const float* __restrict__ x,
                                                        const short* __restrict__ wp,
                                                        float* __restrict__ out,
                                                        float* __restrict__ ws) {
    const int bid = blockIdx.x;
    const int b   = bid >> 10;
    const int od  = (bid >> 4) & 63;
    const int oh0 = (bid & 15) << 2;
    const int t   = threadIdx.x;
    const int wv  = t >> 6;
    const int l   = t & 63;
    const int l15 = l & 15;
    const int lhi = l >> 4;

    const float* xb  = x + (size_t)b * (D_*H_*W_*CI);
    const short* wpb = wp + (size_t)b * (27*2048);

    // xlds[g][r][c] of 8-bf16 units: conflict-free lane-contiguous ds_read_b128
    __shared__ short xlds[XUNITS*8];   // 19584 B
    __shared__ float lsum[4][64];
    __shared__ float lsq[4][64];

    f32x4 acc[2][4];
#pragma unroll
    for (int mf = 0; mf < 2; ++mf)
#pragma unroll
        for (int nf = 0; nf < 4; ++nf)
            acc[mf][nf] = (f32x4){0.f, 0.f, 0.f, 0.f};

    for (int kd = 0; kd < 3; ++kd) {
        const int id = od*2 + kd;
        if (id >= D_) break;                        // block-uniform (od=63 only)
        const float* xsl = xb + (size_t)id * (H_*W_*CI);

        __syncthreads();                            // previous slice's reads done
        for (int u = t; u < XUNITS; u += 256) {
            int c  = u % XC;
            int rc = u / XC;
            int r  = rc % XR;
            int g  = rc / XR;
            int ih = oh0*2 + r;
            int iw = c - 1;
            short8 v = (short8){0,0,0,0,0,0,0,0};
            if (ih < H_ && (unsigned)iw < (unsigned)W_) {
                const float* p = xsl + (size_t)ih*(W_*CI) + iw*CI + g*8;
                v = pack8(*(const float4*)p, *(const float4*)(p + 4));
            }
            *(short8*)(xlds + (size_t)u*8) = v;
        }
        __syncthreads();

        const short* wkd = wpb + (size_t)kd*(9*2048) + l*8;
#pragma unroll
        for (int kh = 0; kh < 3; ++kh) {
#pragma unroll
            for (int kw = 0; kw < 3; ++kw) {
                const short* wpt = wkd + (kh*3 + kw)*2048;
                short8 bf0 = *(const short8*)(wpt);
                short8 bf1 = *(const short8*)(wpt + 512);
                short8 bf2 = *(const short8*)(wpt + 1024);
                short8 bf3 = *(const short8*)(wpt + 1536);
                const int r = 2*wv + kh;
#pragma unroll
                for (int mf = 0; mf < 2; ++mf) {
                    int c = mf*16 + l15 + kw;
                    short8 a = *(const short8*)(xlds + (((lhi*XR + r)*XC + c) * 8));
                    acc[mf][0] = __builtin_amdgcn_mfma_f32_16x16x32_bf16(a, bf0, acc[mf][0], 0,0,0);
                    acc[mf][1] = __builtin_amdgcn_mfma_f32_16x16x32_bf16(a, bf1, acc[mf][1], 0,0,0);
                    acc[mf][2] = __builtin_amdgcn_mfma_f32_16x16x32_bf16(a, bf2, acc[mf][2], 0,0,0);
                    acc[mf][3] = __builtin_amdgcn_mfma_f32_16x16x32_bf16(a, bf3, acc[mf][3], 0,0,0);
                }
            }
        }
    }

    // C-write. C/D: row = lhi*4 + r, col = l15 [m89]
    const int oh = oh0 + wv;
    float* yb = out + (size_t)((b*OD + od)*OH + oh) * (OW*CO);
#pragma unroll
    for (int mf = 0; mf < 2; ++mf)
#pragma unroll
        for (int nf = 0; nf < 4; ++nf)
#pragma unroll
            for (int r = 0; r < 4; ++r) {
                int ow = mf*16 + lhi*4 + r;
                int co = nf*16 + l15;
                yb[ow*CO + co] = acc[mf][nf][r];
            }

    // Fused InstanceNorm stats
    float csum[4], csq[4];
#pragma unroll
    for (int nf = 0; nf < 4; ++nf) {
        float s = 0.f, q = 0.f;
#pragma unroll
        for (int mf = 0; mf < 2; ++mf)
#pragma unroll
            for (int r = 0; r < 4; ++r) {
                float v = acc[mf][nf][r];
                s += v;
                q = fmaf(v, v, q);
            }
        s += __shfl_xor(s, 16, 64); s += __shfl_xor(s, 32, 64);
        q += __shfl_xor(q, 16, 64); q += __shfl_xor(q, 32, 64);
        csum[nf] = s; csq[nf] = q;
    }
    if (lhi == 0) {
#pragma unroll
        for (int nf = 0; nf < 4; ++nf) {
            lsum[wv][nf*16 + l15] = csum[nf];
            lsq[wv][nf*16 + l15]  = csq[nf];
        }
    }
    __syncthreads();
    if (t < 64) {
        float s = lsum[0][t] + lsum[1][t] + lsum[2][t] + lsum[3][t];
        float q = lsq[0][t]  + lsq[1][t]  + lsq[2][t]  + lsq[3][t];
        atomicAdd(&ws[b*64 + t], s);
        atomicAdd(&ws[256 + b*64 + t], q);
    }
}

// ws[0..255]=sum, ws[256..511]=sumsq  ->  ws[512..767]=scale, ws[768..1023]=shift
__global__ __launch_bounds__(256) void finalize_kernel(float* ws,
                                                       const float* __restrict__ gamma,
                                                       const float* __restrict__ beta) {
    int t = threadIdx.x;       // t = b*64 + co
    int co = t & 63;
    const float invS = 1.0f / (float)S_SPATIAL;
    float sum = ws[t];
    float sq  = ws[256 + t];
    float mu  = sum * invS;
    float var = sq * invS - mu*mu;
    float scale = rsqrtf(var + EPS) * gamma[co];
    ws[512 + t] = scale;
    ws[768 + t] = beta[co] - mu*scale;
}

// In-place normalize + leaky relu, float4 per thread.
__global__ __launch_bounds__(256) void norm_kernel(float* __restrict__ y,
                                                   const float* __restrict__ ws) {
    size_t i = (size_t)blockIdx.x * 256 + threadIdx.x;  // float4 index, total 8388608
    int b = (int)(i >> 21);                              // 2097152 float4 per sample
    const float4* scp = (const float4*)(ws + 512 + b*64);
    const float4* shp = (const float4*)(ws + 768 + b*64);
    float4 sc = scp[i & 15];
    float4 sh = shp[i & 15];
    float4 v = ((const float4*)y)[i];
    float4 r;
    r.x = fmaf(v.x, sc.x, sh.x);
    r.y = fmaf(v.y, sc.y, sh.y);
    r.z = fmaf(v.z, sc.z, sh.z);
    r.w = fmaf(v.w, sc.w, sh.w);
    r.x = r.x >= 0.f ? r.x : ALPHA * r.x;
    r.y = r.y >= 0.f ? r.y : ALPHA * r.y;
    r.z = r.z >= 0.f ? r.z : ALPHA * r.z;
    r.w = r.w >= 0.f ? r.w : ALPHA * r.w;
    ((float4*)y)[i] = r;
}

extern "C" void kernel_launch(void* const* d_in, const int* in_sizes, int n_in,
                              void* d_out, int out_size, void* d_ws, size_t ws_size,
                              hipStream_t stream) {
    const float* x     = (const float*)d_in[0];
    const float* w     = (const float*)d_in[1];
    const float* gamma = (const float*)d_in[2];
    const float* beta  = (const float*)d_in[3];
    float* out = (float*)d_out;
    float* ws  = (float*)d_ws;
    short* wp  = (short*)((char*)d_ws + 4096);   // bf16 B-fragments (442368 B)

    zero_ws_kernel<<<1, 512, 0, stream>>>(ws);
    wprep_kernel<<<B_*27*4, 64, 0, stream>>>(w, wp);
    conv_mfma_kernel<<<B_*OD*(OH/4), 256, 0, stream>>>(x, wp, out, ws);
    finalize_kernel<<<1, 256, 0, stream>>>(ws, gamma, beta);
    norm_kernel<<<32768, 256, 0, stream>>>(out, ws);
}

// Round 7
// 216.620 us; speedup vs baseline: 1.1064x; 1.1064x over previous
//
#include <hip/hip_runtime.h>
#include <hip/hip_bf16.h>

#define B_ 4
#define D_ 128
#define H_ 128
#define W_ 32
#define CI 32
#define CO 64
#define OD 64
#define OH 64
#define OW 32
#define S_SPATIAL (OD*OH*OW)   // 131072
#define EPS 1e-5f
#define ALPHA 0.2f

#define XROWS 9                 // ih rows per kd-slice tile (oh-quad span)
#define ROWF 1024               // floats per ih row: 32 iw * 32 ci
#define SLICEF (XROWS*ROWF)     // 9216 floats = 36864 B
#define PLANEF (H_*ROWF)        // floats per id plane

typedef __attribute__((ext_vector_type(8))) short short8;
typedef __attribute__((ext_vector_type(4))) float f32x4;
typedef __attribute__((ext_vector_type(4))) unsigned u32x4;

__device__ inline short f2bf(float f) {
    // native RNE cvt -> compiler fuses pairs into v_cvt_pk_bf16_f32
    return __builtin_bit_cast(short, __float2bfloat16(f));
}

__device__ inline short8 pack8(float4 a, float4 b) {
    short8 r;
    r[0]=f2bf(a.x); r[1]=f2bf(a.y); r[2]=f2bf(a.z); r[3]=f2bf(a.w);
    r[4]=f2bf(b.x); r[5]=f2bf(b.y); r[6]=f2bf(b.z); r[7]=f2bf(b.w);
    return r;
}

__device__ inline short8 mask_frag(short8 v, unsigned m) {
    u32x4 u = __builtin_bit_cast(u32x4, v);
    u[0]&=m; u[1]&=m; u[2]&=m; u[3]&=m;
    return __builtin_bit_cast(short8, u);
}

__device__ inline void gload16(const float* g, const float* l) {
    // async 16B/lane global->LDS DMA; LDS dest = uniform base + lane*16
    __builtin_amdgcn_global_load_lds(
        (const __attribute__((address_space(1))) void*)g,
        (__attribute__((address_space(3))) void*)l, 16, 0, 0);
}

__global__ __launch_bounds__(512) void zero_ws_kernel(float* ws) {
    ws[threadIdx.x] = 0.f;   // 512 floats: sums + sumsqs
}

// Repack w[b,kd,kh,kw,ci,co] f32 -> bf16 lane-ordered B-fragments.
__global__ __launch_bounds__(64) void wprep_kernel(const float* __restrict__ w,
                                                   short* __restrict__ wp) {
    int blk = blockIdx.x;          // ((b*27+tap)*4+nf)
    int nf  = blk & 3;
    int tb  = blk >> 2;            // b*27+tap
    int l   = threadIdx.x;
    int l15 = l & 15, lhi = l >> 4;
    const float* wsrc = w + (size_t)tb * (CI*CO);   // [ci][co]
    short8 v;
#pragma unroll
    for (int j = 0; j < 8; ++j)
        v[j] = f2bf(wsrc[(lhi*8 + j)*CO + nf*16 + l15]);
    *(short8*)(wp + (size_t)blk*512 + l*8) = v;
}

// Implicit-GEMM conv; x staged f32 via fire-and-forget global_load_lds,
// double-buffered per kd-slice, counted vmcnt(9) (never 0 mid-loop),
// raw s_barrier + sched_barrier(0). XOR-swizzled LDS (both-sides: pre-swizzled
// global source + swizzled ds_read addr). cvt f32->bf16 at A-frag build.
// Block = (b, od, oh-quad); wave wv owns oh row oh0+wv.
__global__ __launch_bounds__(256, 2) void conv_mfma_kernel(const float* __restrict__ x,
                                                           const short* __restrict__ wp,
                                                           float* __restrict__ out,
                                                           float* __restrict__ ws) {
    const int bid = blockIdx.x;
    const int b   = bid >> 10;
    const int od  = (bid >> 4) & 63;
    const int oh0 = (bid & 15) << 2;
    const int t   = threadIdx.x;
    const int wv  = t >> 6;
    const int l   = t & 63;
    const int l15 = l & 15;
    const int lhi = l >> 4;

    const float* xb  = x + (size_t)b * (D_*PLANEF);
    const short* wpb = wp + (size_t)b * (27*2048);

    __shared__ __align__(16) float xbuf[2][SLICEF];   // 73728 B
    __shared__ float lsum[4][64];
    __shared__ float lsq[4][64];

    // per-lane pre-swizzled source offset within a 1KB segment (floats):
    // lnF = (l*16B ^ ((l>>3 &7)<<4)) / 4  -> LDS[s] holds x[s ^ ((s>>7&7)<<4)]
    const int lnF = (l << 2) ^ ((l & 0x38) >> 1);
    const int oh02 = oh0 * 2;

    // wave wv stages segments s = wv*9 .. wv*9+8 (row r=s>>2, quarter q=s&3)
    auto stage = [&](const float* xsl, const float* buf) {
#pragma unroll
        for (int j = 0; j < 9; ++j) {
            int s = wv*9 + j;
            int r = s >> 2, q = s & 3;
            int ih = oh02 + r; if (ih > H_-1) ih = H_-1;   // clamp; OOB rows never computed
            gload16(xsl + (size_t)ih*ROWF + q*256 + lnF, buf + r*ROWF + q*256);
        }
    };

    f32x4 acc[2][4];
#pragma unroll
    for (int mf = 0; mf < 2; ++mf)
#pragma unroll
        for (int nf = 0; nf < 4; ++nf)
            acc[mf][nf] = (f32x4){0.f, 0.f, 0.f, 0.f};

    const unsigned mlo = (l15 == 0)  ? 0u : 0xFFFFFFFFu;  // kw=0, mf=0 edge
    const unsigned mhi = (l15 == 15) ? 0u : 0xFFFFFFFFu;  // kw=2, mf=1 edge
    const int ohw2 = 2*(oh0 + wv);

    auto compute = [&](int kd, const float* buf) {
        const short* wkd = wpb + (size_t)kd*(9*2048) + l*8;
#pragma unroll
        for (int kh = 0; kh < 3; ++kh) {
            short8 bf[3][4];
#pragma unroll
            for (int kw = 0; kw < 3; ++kw)
#pragma unroll
                for (int nf = 0; nf < 4; ++nf)
                    bf[kw][nf] = *(const short8*)(wkd + (kh*3 + kw)*2048 + nf*512);
            if (ohw2 + kh < H_) {                       // wave-uniform H guard
                const float* pr = buf + (2*wv + kh)*ROWF;
#pragma unroll
                for (int kw = 0; kw < 3; ++kw) {
#pragma unroll
                    for (int mf = 0; mf < 2; ++mf) {
                        int iw = mf*16 + l15 + kw - 1;
                        iw = iw < 0 ? 0 : (iw > 31 ? 31 : iw);
                        int o  = iw*32 + lhi*8;
                        int x4 = (iw & 7) << 2;
                        float4 v0 = *(const float4*)(pr + (o ^ x4));
                        float4 v1 = *(const float4*)(pr + ((o + 4) ^ x4));
                        short8 a = pack8(v0, v1);
                        if (kw == 0 && mf == 0) a = mask_frag(a, mlo);
                        if (kw == 2 && mf == 1) a = mask_frag(a, mhi);
                        acc[mf][0] = __builtin_amdgcn_mfma_f32_16x16x32_bf16(a, bf[kw][0], acc[mf][0], 0,0,0);
                        acc[mf][1] = __builtin_amdgcn_mfma_f32_16x16x32_bf16(a, bf[kw][1], acc[mf][1], 0,0,0);
                        acc[mf][2] = __builtin_amdgcn_mfma_f32_16x16x32_bf16(a, bf[kw][2], acc[mf][2], 0,0,0);
                        acc[mf][3] = __builtin_amdgcn_mfma_f32_16x16x32_bf16(a, bf[kw][3], acc[mf][3], 0,0,0);
                    }
                }
            }
        }
    };

    const int id0 = od*2;
    const float* xsl0 = xb + (size_t)id0 * PLANEF;
    const float* xsl1 = xsl0 + PLANEF;                       // id0+1 <= 127 always
    int id2c = id0 + 2; if (id2c > D_-1) id2c = D_-1;        // clamp (od=63); never computed
    const float* xsl2 = xb + (size_t)id2c * PLANEF;

    stage(xsl0, xbuf[0]);                                    // 9 loads in flight
    stage(xsl1, xbuf[1]);                                    // 18 in flight
    asm volatile("s_waitcnt vmcnt(9)" ::: "memory");         // slice0 arrived
    __builtin_amdgcn_s_barrier();
    __builtin_amdgcn_sched_barrier(0);
    compute(0, xbuf[0]);
    __builtin_amdgcn_s_barrier();                            // all reads of buf0 done
    __builtin_amdgcn_sched_barrier(0);
    stage(xsl2, xbuf[0]);                                    // overwrite buf0
    asm volatile("s_waitcnt vmcnt(9)" ::: "memory");         // slice1 arrived
    __builtin_amdgcn_s_barrier();
    __builtin_amdgcn_sched_barrier(0);
    compute(1, xbuf[1]);
    asm volatile("s_waitcnt vmcnt(0)" ::: "memory");         // slice2 arrived (loop end)
    __builtin_amdgcn_s_barrier();
    __builtin_amdgcn_sched_barrier(0);
    if (id0 + 2 < D_)                                        // block-uniform D guard
        compute(2, xbuf[0]);

    // C-write. C/D: row = lhi*4 + r, col = l15 [m89]
    const int oh = oh0 + wv;
    float* yb = out + (size_t)((b*OD + od)*OH + oh) * (OW*CO);
#pragma unroll
    for (int mf = 0; mf < 2; ++mf)
#pragma unroll
        for (int nf = 0; nf < 4; ++nf)
#pragma unroll
            for (int r = 0; r < 4; ++r) {
                int ow = mf*16 + lhi*4 + r;
                int co = nf*16 + l15;
                yb[ow*CO + co] = acc[mf][nf][r];
            }

    // Fused InstanceNorm stats
    float csum[4], csq[4];
#pragma unroll
    for (int nf = 0; nf < 4; ++nf) {
        float s = 0.f, q = 0.f;
#pragma unroll
        for (int mf = 0; mf < 2; ++mf)
#pragma unroll
            for (int r = 0; r < 4; ++r) {
                float v = acc[mf][nf][r];
                s += v;
                q = fmaf(v, v, q);
            }
        s += __shfl_xor(s, 16, 64); s += __shfl_xor(s, 32, 64);
        q += __shfl_xor(q, 16, 64); q += __shfl_xor(q, 32, 64);
        csum[nf] = s; csq[nf] = q;
    }
    if (lhi == 0) {
#pragma unroll
        for (int nf = 0; nf < 4; ++nf) {
            lsum[wv][nf*16 + l15] = csum[nf];
            lsq[wv][nf*16 + l15]  = csq[nf];
        }
    }
    __syncthreads();
    if (t < 64) {
        float s = lsum[0][t] + lsum[1][t] + lsum[2][t] + lsum[3][t];
        float q = lsq[0][t]  + lsq[1][t]  + lsq[2][t]  + lsq[3][t];
        atomicAdd(&ws[b*64 + t], s);
        atomicAdd(&ws[256 + b*64 + t], q);
    }
}

// ws[0..255]=sum, ws[256..511]=sumsq  ->  ws[512..767]=scale, ws[768..1023]=shift
__global__ __launch_bounds__(256) void finalize_kernel(float* ws,
                                                       const float* __restrict__ gamma,
                                                       const float* __restrict__ beta) {
    int t = threadIdx.x;       // t = b*64 + co
    int co = t & 63;
    const float invS = 1.0f / (float)S_SPATIAL;
    float sum = ws[t];
    float sq  = ws[256 + t];
    float mu  = sum * invS;
    float var = sq * invS - mu*mu;
    float scale = rsqrtf(var + EPS) * gamma[co];
    ws[512 + t] = scale;
    ws[768 + t] = beta[co] - mu*scale;
}

// In-place normalize + leaky relu, float4 per thread.
__global__ __launch_bounds__(256) void norm_kernel(float* __restrict__ y,
                                                   const float* __restrict__ ws) {
    size_t i = (size_t)blockIdx.x * 256 + threadIdx.x;  // float4 index, total 8388608
    int b = (int)(i >> 21);                              // 2097152 float4 per sample
    const float4* scp = (const float4*)(ws + 512 + b*64);
    const float4* shp = (const float4*)(ws + 768 + b*64);
    float4 sc = scp[i & 15];
    float4 sh = shp[i & 15];
    float4 v = ((const float4*)y)[i];
    float4 r;
    r.x = fmaf(v.x, sc.x, sh.x);
    r.y = fmaf(v.y, sc.y, sh.y);
    r.z = fmaf(v.z, sc.z, sh.z);
    r.w = fmaf(v.w, sc.w, sh.w);
    r.x = r.x >= 0.f ? r.x : ALPHA * r.x;
    r.y = r.y >= 0.f ? r.y : ALPHA * r.y;
    r.z = r.z >= 0.f ? r.z : ALPHA * r.z;
    r.w = r.w >= 0.f ? r.w : ALPHA * r.w;
    ((float4*)y)[i] = r;
}

extern "C" void kernel_launch(void* const* d_in, const int* in_sizes, int n_in,
                              void* d_out, int out_size, void* d_ws, size_t ws_size,
                              hipStream_t stream) {
    const float* x     = (const float*)d_in[0];
    const float* w     = (const float*)d_in[1];
    const float* gamma = (const float*)d_in[2];
    const float* beta  = (const float*)d_in[3];
    float* out = (float*)d_out;
    float* ws  = (float*)d_ws;
    short* wp  = (short*)((char*)d_ws + 4096);   // bf16 B-fragments (442368 B)

    zero_ws_kernel<<<1, 512, 0, stream>>>(ws);
    wprep_kernel<<<B_*27*4, 64, 0, stream>>>(w, wp);
    conv_mfma_kernel<<<B_*OD*(OH/4), 256, 0, stream>>>(x, wp, out, ws);
    finalize_kernel<<<1, 256, 0, stream>>>(ws, gamma, beta);
    norm_kernel<<<32768, 256, 0, stream>>>(out, ws);
}